// Round 1
// baseline (4832.948 us; speedup 1.0000x reference)
//
#include <hip/hip_runtime.h>

typedef __bf16 bf16_t;
typedef bf16_t bf16x8 __attribute__((ext_vector_type(8)));
typedef float  f32x4  __attribute__((ext_vector_type(4)));

#define NN   81
#define BB   512
#define BN   41472          // 512*81
#define HD   128
#define EE   1620

// element-index swizzle for 128-wide rows of 2B or 4B elements: keeps 16B
// vector alignment, conflict profile ~= +8 padding, but fits 2x buffers in 64KB
__device__ __forceinline__ int swz(int r, int k) {
    return (r << 7) + ((((k >> 3) ^ (r & 7)) << 3) | (k & 7));
}

// stage 128x128 bf16 weight (already transposed: Wt[n][k]) global -> LDS
__device__ __forceinline__ void stage_w(bf16_t* wsm, const bf16_t* __restrict__ W, int tid) {
    for (int ch = tid; ch < 2048; ch += 256) {
        int n = ch >> 4, gi = ch & 15;
        *(bf16x8*)&wsm[swz(n, gi << 3)] = *(const bf16x8*)(W + n * 128 + (gi << 3));
    }
}

// stage 128 rows of f32 (stride 128) -> bf16 LDS
__device__ __forceinline__ void stage_act_f32(bf16_t* act, const float* __restrict__ src, int tid) {
    for (int ch = tid; ch < 2048; ch += 256) {
        int r = ch >> 4, p = ch & 15;
        const float4 a = *(const float4*)(src + (size_t)r * 128 + p * 8);
        const float4 b = *(const float4*)(src + (size_t)r * 128 + p * 8 + 4);
        bf16x8 o;
        o[0] = (bf16_t)a.x; o[1] = (bf16_t)a.y; o[2] = (bf16_t)a.z; o[3] = (bf16_t)a.w;
        o[4] = (bf16_t)b.x; o[5] = (bf16_t)b.y; o[6] = (bf16_t)b.z; o[7] = (bf16_t)b.w;
        *(bf16x8*)&act[swz(r, p << 3)] = o;
    }
}

// 128x128x128 GEMM: act(MxK) * Wt(N-major KxN) -> acc, 4 waves each 64x64
__device__ __forceinline__ void gemm128(f32x4 (&acc)[4][4], const bf16_t* act, const bf16_t* wsm,
                                        int wm, int wn, int lrow, int q, bool zero) {
    if (zero) {
        f32x4 z = {0.f, 0.f, 0.f, 0.f};
        #pragma unroll
        for (int mt = 0; mt < 4; mt++)
            #pragma unroll
            for (int nt = 0; nt < 4; nt++) acc[mt][nt] = z;
    }
    #pragma unroll
    for (int k0 = 0; k0 < 128; k0 += 32) {
        bf16x8 af[4], wf[4];
        #pragma unroll
        for (int mt = 0; mt < 4; mt++)
            af[mt] = *(const bf16x8*)&act[swz(wm * 64 + mt * 16 + lrow, k0 + q * 8)];
        #pragma unroll
        for (int nt = 0; nt < 4; nt++)
            wf[nt] = *(const bf16x8*)&wsm[swz(wn * 64 + nt * 16 + lrow, k0 + q * 8)];
        #pragma unroll
        for (int mt = 0; mt < 4; mt++)
            #pragma unroll
            for (int nt = 0; nt < 4; nt++)
                acc[mt][nt] = __builtin_amdgcn_mfma_f32_16x16x32_bf16(af[mt], wf[nt], acc[mt][nt], 0, 0, 0);
    }
}

// act <- [relu](acc + bias[col]) as bf16
__device__ __forceinline__ void writeback(bf16_t* act, f32x4 (&acc)[4][4],
                                          const float* __restrict__ bias,
                                          int wm, int wn, int lrow, int q, bool dorelu) {
    #pragma unroll
    for (int nt = 0; nt < 4; nt++) {
        int col = wn * 64 + nt * 16 + lrow;
        float bb = bias[col];
        #pragma unroll
        for (int mt = 0; mt < 4; mt++)
            #pragma unroll
            for (int r = 0; r < 4; r++) {
                int row = wm * 64 + mt * 16 + q * 4 + r;
                float v = acc[mt][nt][r] + bb;
                if (dorelu) v = fmaxf(v, 0.f);
                act[swz(row, col)] = (bf16_t)v;
            }
    }
}

// ---------------- prep kernels ----------------

__global__ __launch_bounds__(256) void k_embed(const float* __restrict__ x, const float* __restrict__ W_in,
                                               const float* __restrict__ b_in, const float* __restrict__ pos,
                                               float* __restrict__ h) {
    int idx = blockIdx.x * 256 + threadIdx.x;   // < BN*128
    int row = idx >> 7, col = idx & 127;
    int n = row % NN;
    const float* xr = x + (size_t)row * 10;
    float s = b_in[col] + pos[n * 128 + col];
    #pragma unroll
    for (int k = 0; k < 10; k++) s += xr[k] * W_in[k * 128 + col];
    h[idx] = s;
}

__global__ __launch_bounds__(256) void k_transpose(const float* __restrict__ src, bf16_t* __restrict__ dst) {
    int idx = blockIdx.x * 256 + threadIdx.x;   // < 16384
    int n = idx >> 7, k = idx & 127;
    dst[idx] = (bf16_t)src[k * 128 + n];        // dst[n*128+k] = W[k][n]
}

template <bool BF16OUT>
__global__ __launch_bounds__(256, 2) void k_simple_gemm(const float* __restrict__ in,
                                                        const bf16_t* __restrict__ Wt,
                                                        const float* __restrict__ bias,
                                                        void* __restrict__ out) {
    __shared__ __align__(16) char smem[65536];
    bf16_t* act = (bf16_t*)smem;
    bf16_t* wsm = (bf16_t*)(smem + 32768);
    int tid = threadIdx.x;
    size_t i0 = (size_t)blockIdx.x * 128;
    int lane = tid & 63, wid = tid >> 6;
    int wm = wid >> 1, wn = wid & 1, lrow = lane & 15, q = lane >> 4;

    stage_act_f32(act, in + i0 * 128, tid);
    stage_w(wsm, Wt, tid);
    __syncthreads();
    f32x4 acc[4][4];
    gemm128(acc, act, wsm, wm, wn, lrow, q, true);
    #pragma unroll
    for (int nt = 0; nt < 4; nt++) {
        int col = wn * 64 + nt * 16 + lrow;
        float bb = bias ? bias[col] : 0.f;
        #pragma unroll
        for (int mt = 0; mt < 4; mt++)
            #pragma unroll
            for (int r = 0; r < 4; r++) {
                int row = wm * 64 + mt * 16 + q * 4 + r;
                float v = acc[mt][nt][r] + bb;
                if (BF16OUT) ((bf16_t*)out)[(i0 + row) * 128 + col] = (bf16_t)v;
                else         ((float*)out)[(i0 + row) * 128 + col] = v;
            }
    }
}

// ---------------- edge (message) kernel ----------------
// tile: 1 batch x 120 edges (6 dst nodes). rows 0..119 <-> edges e0+r, dst = n0 + r/20.
__global__ __launch_bounds__(256, 2) void k_edge(const bf16_t* __restrict__ P, const bf16_t* __restrict__ Q,
                                                 const int* __restrict__ src, const bf16_t* __restrict__ Wb,
                                                 const float* __restrict__ mb0, const float* __restrict__ mb1,
                                                 const float* __restrict__ mb2, const float* __restrict__ mb3,
                                                 float* __restrict__ agg) {
    __shared__ __align__(16) char smem[65536];
    bf16_t* act = (bf16_t*)smem;
    bf16_t* wsm = (bf16_t*)(smem + 32768);
    float*  msg = (float*)smem;                 // overlays both after last GEMM
    int tid = threadIdx.x;
    int g = blockIdx.x, b = blockIdx.y;
    int e0 = g * 120, n0 = g * 6;
    int nreal = (e0 + 120 <= EE) ? 120 : (EE - e0);   // 120 or 60
    int lane = tid & 63, wid = tid >> 6;
    int wm = wid >> 1, wn = wid & 1, lrow = lane & 15, q = lane >> 4;

    // layer-0: act0 = relu(P[src] + Q[dst] + mb0), staged as bf16
    for (int ch = tid; ch < 2048; ch += 256) {
        int r = ch >> 4, p = ch & 15;
        bf16x8 o;
        if (r < nreal) {
            int e = e0 + r;
            int sn = src[e];
            int dn = n0 + r / 20;
            bf16x8 pv = *(const bf16x8*)(P + ((size_t)b * NN + sn) * 128 + p * 8);
            bf16x8 qv = *(const bf16x8*)(Q + ((size_t)b * NN + dn) * 128 + p * 8);
            #pragma unroll
            for (int i = 0; i < 8; i++) {
                float t = (float)pv[i] + (float)qv[i] + mb0[p * 8 + i];
                o[i] = (bf16_t)fmaxf(t, 0.f);
            }
        } else {
            #pragma unroll
            for (int i = 0; i < 8; i++) o[i] = (bf16_t)0.f;
        }
        *(bf16x8*)&act[swz(r, p << 3)] = o;
    }
    stage_w(wsm, Wb + 2 * 16384, tid);          // mW1t
    __syncthreads();

    f32x4 acc[4][4];
    gemm128(acc, act, wsm, wm, wn, lrow, q, true);
    __syncthreads();
    writeback(act, acc, mb1, wm, wn, lrow, q, true);
    stage_w(wsm, Wb + 3 * 16384, tid);          // mW2t
    __syncthreads();
    gemm128(acc, act, wsm, wm, wn, lrow, q, true);
    __syncthreads();
    writeback(act, acc, mb2, wm, wn, lrow, q, true);
    stage_w(wsm, Wb + 4 * 16384, tid);          // mW3t
    __syncthreads();
    gemm128(acc, act, wsm, wm, wn, lrow, q, true);
    __syncthreads();

    // final messages (f32) to LDS, then 20-row group reduction -> agg (no atomics)
    #pragma unroll
    for (int nt = 0; nt < 4; nt++) {
        int col = wn * 64 + nt * 16 + lrow;
        float bb = mb3[col];
        #pragma unroll
        for (int mt = 0; mt < 4; mt++)
            #pragma unroll
            for (int r = 0; r < 4; r++) {
                int row = wm * 64 + mt * 16 + q * 4 + r;
                msg[swz(row, col)] = acc[mt][nt][r] + bb;
            }
    }
    __syncthreads();
    int nodes = (nreal == 120) ? 6 : 3;
    for (int o = tid; o < 768; o += 256) {
        int j = o >> 7, c = o & 127;
        if (j < nodes) {
            float s = 0.f;
            #pragma unroll
            for (int i = 0; i < 20; i++) s += msg[swz(20 * j + i, c)];
            agg[((size_t)b * NN + n0 + j) * 128 + c] = s;
        }
    }
}

// ---------------- node kernel: node MLP + residual + LN + next-step P/Q ----------------
__global__ __launch_bounds__(256, 2) void k_node(float* __restrict__ h, const float* __restrict__ agg,
                                                 const float* __restrict__ C2, const bf16_t* __restrict__ Wb,
                                                 const float* __restrict__ nb1, const float* __restrict__ nb2,
                                                 const float* __restrict__ nb3, const float* __restrict__ ln_g,
                                                 const float* __restrict__ ln_b,
                                                 bf16_t* __restrict__ Pd, bf16_t* __restrict__ Qd) {
    __shared__ __align__(16) char smem[65536];
    bf16_t* act = (bf16_t*)smem;
    bf16_t* wsm = (bf16_t*)(smem + 32768);
    float*  st  = (float*)(smem + 32768);       // 128 rows x {s1,s2} x 2 halves
    int tid = threadIdx.x;
    size_t i0 = (size_t)blockIdx.x * 128;
    int lane = tid & 63, wid = tid >> 6;
    int wm = wid >> 1, wn = wid & 1, lrow = lane & 15, q = lane >> 4;

    f32x4 acc[4][4];
    stage_act_f32(act, h + i0 * 128, tid);
    stage_w(wsm, Wb + 5 * 16384, tid);          // nW0at (h part)
    __syncthreads();
    gemm128(acc, act, wsm, wm, wn, lrow, q, true);
    __syncthreads();
    stage_act_f32(act, agg + i0 * 128, tid);
    stage_w(wsm, Wb + 6 * 16384, tid);          // nW0ct (agg part)
    __syncthreads();
    gemm128(acc, act, wsm, wm, wn, lrow, q, false);   // accumulate
    __syncthreads();
    // u0 = relu(acc + C2)   (C2 = x_embed@nW0b + nb0, precomputed)
    #pragma unroll
    for (int nt = 0; nt < 4; nt++) {
        int col = wn * 64 + nt * 16 + lrow;
        #pragma unroll
        for (int mt = 0; mt < 4; mt++)
            #pragma unroll
            for (int r = 0; r < 4; r++) {
                int row = wm * 64 + mt * 16 + q * 4 + r;
                float v = acc[mt][nt][r] + C2[(i0 + row) * 128 + col];
                act[swz(row, col)] = (bf16_t)fmaxf(v, 0.f);
            }
    }
    stage_w(wsm, Wb + 7 * 16384, tid);          // nW1t
    __syncthreads();
    gemm128(acc, act, wsm, wm, wn, lrow, q, true);
    __syncthreads();
    writeback(act, acc, nb1, wm, wn, lrow, q, true);
    stage_w(wsm, Wb + 8 * 16384, tid);          // nW2t
    __syncthreads();
    gemm128(acc, act, wsm, wm, wn, lrow, q, true);
    __syncthreads();
    writeback(act, acc, nb2, wm, wn, lrow, q, true);
    stage_w(wsm, Wb + 9 * 16384, tid);          // nW3t
    __syncthreads();
    gemm128(acc, act, wsm, wm, wn, lrow, q, true);
    __syncthreads();                             // (A)

    // v = u3 + nb3 + h  (residual), accumulate LN stats
    float s1[4][4], s2[4][4];
    #pragma unroll
    for (int mt = 0; mt < 4; mt++)
        #pragma unroll
        for (int r = 0; r < 4; r++) { s1[mt][r] = 0.f; s2[mt][r] = 0.f; }
    #pragma unroll
    for (int nt = 0; nt < 4; nt++) {
        int col = wn * 64 + nt * 16 + lrow;
        float bb = nb3[col];
        #pragma unroll
        for (int mt = 0; mt < 4; mt++)
            #pragma unroll
            for (int r = 0; r < 4; r++) {
                int row = wm * 64 + mt * 16 + q * 4 + r;
                float v = acc[mt][nt][r] + bb + h[(i0 + row) * 128 + col];
                acc[mt][nt][r] = v;
                s1[mt][r] += v;
                s2[mt][r] += v * v;
            }
    }
    #pragma unroll
    for (int mt = 0; mt < 4; mt++)
        #pragma unroll
        for (int r = 0; r < 4; r++) {
            float a = s1[mt][r], b2 = s2[mt][r];
            #pragma unroll
            for (int off = 1; off < 16; off <<= 1) {
                a  += __shfl_xor(a, off);
                b2 += __shfl_xor(b2, off);
            }
            s1[mt][r] = a; s2[mt][r] = b2;
        }
    if (lrow == 0) {
        #pragma unroll
        for (int mt = 0; mt < 4; mt++)
            #pragma unroll
            for (int r = 0; r < 4; r++) {
                int row = wm * 64 + mt * 16 + q * 4 + r;
                st[row * 4 + wn * 2 + 0] = s1[mt][r];
                st[row * 4 + wn * 2 + 1] = s2[mt][r];
            }
    }
    __syncthreads();                             // (B)
    float mu[4][4], rs[4][4];
    #pragma unroll
    for (int mt = 0; mt < 4; mt++)
        #pragma unroll
        for (int r = 0; r < 4; r++) {
            int row = wm * 64 + mt * 16 + q * 4 + r;
            float m  = (st[row * 4 + 0] + st[row * 4 + 2]) * (1.f / 128.f);
            float m2 = (st[row * 4 + 1] + st[row * 4 + 3]) * (1.f / 128.f);
            mu[mt][r] = m;
            rs[mt][r] = rsqrtf(m2 - m * m + 1e-5f);
        }
    // apply LN: h (f32 global) + act (bf16 LDS for P/Q GEMM)
    #pragma unroll
    for (int nt = 0; nt < 4; nt++) {
        int col = wn * 64 + nt * 16 + lrow;
        float gg = ln_g[col], bb = ln_b[col];
        #pragma unroll
        for (int mt = 0; mt < 4; mt++)
            #pragma unroll
            for (int r = 0; r < 4; r++) {
                int row = wm * 64 + mt * 16 + q * 4 + r;
                float hn = (acc[mt][nt][r] - mu[mt][r]) * rs[mt][r] * gg + bb;
                h[(i0 + row) * 128 + col] = hn;
                act[swz(row, col)] = (bf16_t)hn;
            }
    }
    __syncthreads();                             // (C)
    stage_w(wsm, Wb + 0 * 16384, tid);          // mW0at
    __syncthreads();                             // (D)
    gemm128(acc, act, wsm, wm, wn, lrow, q, true);
    #pragma unroll
    for (int nt = 0; nt < 4; nt++) {
        int col = wn * 64 + nt * 16 + lrow;
        #pragma unroll
        for (int mt = 0; mt < 4; mt++)
            #pragma unroll
            for (int r = 0; r < 4; r++) {
                int row = wm * 64 + mt * 16 + q * 4 + r;
                Pd[(i0 + row) * 128 + col] = (bf16_t)acc[mt][nt][r];
            }
    }
    __syncthreads();                             // (E)
    stage_w(wsm, Wb + 1 * 16384, tid);          // mW0bt
    __syncthreads();                             // (F)
    gemm128(acc, act, wsm, wm, wn, lrow, q, true);
    #pragma unroll
    for (int nt = 0; nt < 4; nt++) {
        int col = wn * 64 + nt * 16 + lrow;
        #pragma unroll
        for (int mt = 0; mt < 4; mt++)
            #pragma unroll
            for (int r = 0; r < 4; r++) {
                int row = wm * 64 + mt * 16 + q * 4 + r;
                Qd[(i0 + row) * 128 + col] = (bf16_t)acc[mt][nt][r];
            }
    }
}

__global__ __launch_bounds__(256) void k_out(const float* __restrict__ h, const float* __restrict__ W_out,
                                             const float* __restrict__ b_out, float* __restrict__ out) {
    int idx = blockIdx.x * 256 + threadIdx.x;   // < BN*9
    int row = idx / 9, o = idx - row * 9;
    const float* hr = h + (size_t)row * 128;
    float s = b_out[o];
    #pragma unroll 4
    for (int k = 0; k < 128; k++) s += hr[k] * W_out[k * 9 + o];
    out[idx] = s;
}

extern "C" void kernel_launch(void* const* d_in, const int* in_sizes, int n_in,
                              void* d_out, int out_size, void* d_ws, size_t ws_size,
                              hipStream_t stream) {
    const float* x    = (const float*)d_in[0];
    const int*   src  = (const int*)d_in[1];
    const float* W_in = (const float*)d_in[3];
    const float* b_in = (const float*)d_in[4];
    const float* pos  = (const float*)d_in[5];
    const float* mW0  = (const float*)d_in[6];
    const float* mb0  = (const float*)d_in[7];
    const float* mW1  = (const float*)d_in[8];
    const float* mb1  = (const float*)d_in[9];
    const float* mW2  = (const float*)d_in[10];
    const float* mb2  = (const float*)d_in[11];
    const float* mW3  = (const float*)d_in[12];
    const float* mb3  = (const float*)d_in[13];
    const float* nW0  = (const float*)d_in[14];
    const float* nb0  = (const float*)d_in[15];
    const float* nW1  = (const float*)d_in[16];
    const float* nb1  = (const float*)d_in[17];
    const float* nW2  = (const float*)d_in[18];
    const float* nb2  = (const float*)d_in[19];
    const float* nW3  = (const float*)d_in[20];
    const float* nb3  = (const float*)d_in[21];
    const float* ln_g = (const float*)d_in[22];
    const float* ln_b = (const float*)d_in[23];
    const float* W_out= (const float*)d_in[24];
    const float* b_out= (const float*)d_in[25];

    char* ws = (char*)d_ws;
    float*  h   = (float*)ws;                       // 21,233,664 B (also x_embed)
    float*  C2  = (float*)(ws + 21233664);          // 21,233,664 B
    float*  agg = (float*)(ws + 42467328);          // 21,233,664 B
    bf16_t* P   = (bf16_t*)(ws + 63700992);         // 10,616,832 B
    bf16_t* Q   = (bf16_t*)(ws + 74317824);         // 10,616,832 B
    bf16_t* Wb  = (bf16_t*)(ws + 84934656);         // 11 * 32,768 B  (bf16, transposed)

    k_embed<<<20736, 256, 0, stream>>>(x, W_in, b_in, pos, h);

    // transposed bf16 weights: [0]mW0a [1]mW0b [2]mW1 [3]mW2 [4]mW3
    //                          [5]nW0a(h) [6]nW0c(agg) [7]nW1 [8]nW2 [9]nW3 [10]nW0b(x)
    const float* tsrc[11] = {mW0, mW0 + 16384, mW1, mW2, mW3,
                             nW0, nW0 + 32768, nW1, nW2, nW3, nW0 + 16384};
    for (int i = 0; i < 11; i++)
        k_transpose<<<64, 256, 0, stream>>>(tsrc[i], Wb + i * 16384);

    k_simple_gemm<false><<<324, 256, 0, stream>>>(h, Wb + 10 * 16384, nb0, C2);   // C2
    k_simple_gemm<true ><<<324, 256, 0, stream>>>(h, Wb + 0 * 16384, nullptr, P); // P0
    k_simple_gemm<true ><<<324, 256, 0, stream>>>(h, Wb + 1 * 16384, nullptr, Q); // Q0

    for (int s = 0; s < 16; s++) {
        k_edge<<<dim3(14, 512), 256, 0, stream>>>(P, Q, src, Wb, mb0, mb1, mb2, mb3, agg);
        k_node<<<324, 256, 0, stream>>>(h, agg, C2, Wb, nb1, nb2, nb3, ln_g, ln_b, P, Q);
    }
    k_out<<<1458, 256, 0, stream>>>(h, W_out, b_out, (float*)d_out);
}

// Round 2
// 3886.096 us; speedup vs baseline: 1.2437x; 1.2437x over previous
//
#include <hip/hip_runtime.h>

typedef __bf16 bf16_t;
typedef bf16_t bf16x8 __attribute__((ext_vector_type(8)));
typedef bf16_t bf16x4 __attribute__((ext_vector_type(4)));
typedef float  f32x4  __attribute__((ext_vector_type(4)));

#define NN   81
#define BB   512
#define BN   41472          // 512*81
#define HD   128
#define EE   1620

// element-index swizzle for 128-wide rows of 2B or 4B elements: keeps 16B
// vector alignment, conflict profile ~= +8 padding, fits 2x buffers in 64KB
__device__ __forceinline__ int swz(int r, int k) {
    return (r << 7) + ((((k >> 3) ^ (r & 7)) << 3) | (k & 7));
}

// stage 128x128 bf16 weight (already transposed: Wt[n][k]) global -> LDS
__device__ __forceinline__ void stage_w(bf16_t* wsm, const bf16_t* __restrict__ W, int tid) {
    for (int ch = tid; ch < 2048; ch += 256) {
        int n = ch >> 4, gi = ch & 15;
        *(bf16x8*)&wsm[swz(n, gi << 3)] = *(const bf16x8*)(W + n * 128 + (gi << 3));
    }
}

// stage 128 rows of f32 (stride 128) -> bf16 LDS
__device__ __forceinline__ void stage_act_f32(bf16_t* act, const float* __restrict__ src, int tid) {
    for (int ch = tid; ch < 2048; ch += 256) {
        int r = ch >> 4, p = ch & 15;
        const float4 a = *(const float4*)(src + (size_t)r * 128 + p * 8);
        const float4 b = *(const float4*)(src + (size_t)r * 128 + p * 8 + 4);
        bf16x8 o;
        o[0] = (bf16_t)a.x; o[1] = (bf16_t)a.y; o[2] = (bf16_t)a.z; o[3] = (bf16_t)a.w;
        o[4] = (bf16_t)b.x; o[5] = (bf16_t)b.y; o[6] = (bf16_t)b.z; o[7] = (bf16_t)b.w;
        *(bf16x8*)&act[swz(r, p << 3)] = o;
    }
}

// stage 128 rows of bf16 (stride 128) -> LDS (no convert)
__device__ __forceinline__ void stage_act_bf16(bf16_t* act, const bf16_t* __restrict__ src, int tid) {
    for (int ch = tid; ch < 2048; ch += 256) {
        int r = ch >> 4, p = ch & 15;
        *(bf16x8*)&act[swz(r, p << 3)] = *(const bf16x8*)(src + (size_t)r * 128 + (p << 3));
    }
}

// 128x128x128 GEMM, 4 waves each 64x64.
// SWAP=false: acc[mt][nt] = D[m][n] (row=m), as round-1.
// SWAP=true : acc[nt][mt] = D[n][m] (row=n=feature, col=m=edge-row) -> packed wb.
template <bool SWAP>
__device__ __forceinline__ void gemm128(f32x4 (&acc)[4][4], const bf16_t* act, const bf16_t* wsm,
                                        int wm, int wn, int lrow, int q, bool zero) {
    if (zero) {
        f32x4 z = {0.f, 0.f, 0.f, 0.f};
        #pragma unroll
        for (int i = 0; i < 4; i++)
            #pragma unroll
            for (int j = 0; j < 4; j++) acc[i][j] = z;
    }
    #pragma unroll
    for (int k0 = 0; k0 < 128; k0 += 32) {
        bf16x8 af[4], wf[4];
        #pragma unroll
        for (int mt = 0; mt < 4; mt++)
            af[mt] = *(const bf16x8*)&act[swz(wm * 64 + mt * 16 + lrow, k0 + q * 8)];
        #pragma unroll
        for (int nt = 0; nt < 4; nt++)
            wf[nt] = *(const bf16x8*)&wsm[swz(wn * 64 + nt * 16 + lrow, k0 + q * 8)];
        #pragma unroll
        for (int i = 0; i < 4; i++)
            #pragma unroll
            for (int j = 0; j < 4; j++) {
                if (SWAP) acc[i][j] = __builtin_amdgcn_mfma_f32_16x16x32_bf16(wf[i], af[j], acc[i][j], 0, 0, 0);
                else      acc[i][j] = __builtin_amdgcn_mfma_f32_16x16x32_bf16(af[i], wf[j], acc[i][j], 0, 0, 0);
            }
    }
}

// swapped-layout writeback: act[m][n..n+3] <- relu(acc + bias), one 8B packed store
__device__ __forceinline__ void wb_swap(bf16_t* act, f32x4 (&acc)[4][4], const float4 (&bias)[4],
                                        int wm, int wn, int lrow, int q) {
    #pragma unroll
    for (int nt = 0; nt < 4; nt++) {
        int nb = wn * 64 + nt * 16 + q * 4;
        #pragma unroll
        for (int mt = 0; mt < 4; mt++) {
            int m = wm * 64 + mt * 16 + lrow;
            bf16x4 o;
            o[0] = (bf16_t)fmaxf(acc[nt][mt][0] + bias[nt].x, 0.f);
            o[1] = (bf16_t)fmaxf(acc[nt][mt][1] + bias[nt].y, 0.f);
            o[2] = (bf16_t)fmaxf(acc[nt][mt][2] + bias[nt].z, 0.f);
            o[3] = (bf16_t)fmaxf(acc[nt][mt][3] + bias[nt].w, 0.f);
            *(bf16x4*)&act[swz(m, nb)] = o;   // nb%8 in {0,4}: 4 elems contiguous post-swizzle
        }
    }
}

// round-1 writeback (row-major acc), used by node kernel
__device__ __forceinline__ void writeback(bf16_t* act, f32x4 (&acc)[4][4],
                                          const float* __restrict__ bias,
                                          int wm, int wn, int lrow, int q, bool dorelu) {
    #pragma unroll
    for (int nt = 0; nt < 4; nt++) {
        int col = wn * 64 + nt * 16 + lrow;
        float bb = bias[col];
        #pragma unroll
        for (int mt = 0; mt < 4; mt++)
            #pragma unroll
            for (int r = 0; r < 4; r++) {
                int row = wm * 64 + mt * 16 + q * 4 + r;
                float v = acc[mt][nt][r] + bb;
                if (dorelu) v = fmaxf(v, 0.f);
                act[swz(row, col)] = (bf16_t)v;
            }
    }
}

// ---------------- prep kernels ----------------

__global__ __launch_bounds__(256) void k_embed(const float* __restrict__ x, const float* __restrict__ W_in,
                                               const float* __restrict__ b_in, const float* __restrict__ pos,
                                               float* __restrict__ h) {
    int idx = blockIdx.x * 256 + threadIdx.x;   // < BN*128
    int row = idx >> 7, col = idx & 127;
    int n = row % NN;
    const float* xr = x + (size_t)row * 10;
    float s = b_in[col] + pos[n * 128 + col];
    #pragma unroll
    for (int k = 0; k < 10; k++) s += xr[k] * W_in[k * 128 + col];
    h[idx] = s;
}

__global__ __launch_bounds__(256) void k_transpose(const float* __restrict__ src, bf16_t* __restrict__ dst) {
    int idx = blockIdx.x * 256 + threadIdx.x;   // < 16384
    int n = idx >> 7, k = idx & 127;
    dst[idx] = (bf16_t)src[k * 128 + n];        // dst[n*128+k] = W[k][n]
}

// Ft[n][k] = (mW3 @ nW0c)[k][n]  (fused edge-final x node-agg weight, f32 math)
__global__ __launch_bounds__(256) void k_fuse(const float* __restrict__ mW3, const float* __restrict__ nW0,
                                              bf16_t* __restrict__ Ft) {
    int idx = blockIdx.x * 256 + threadIdx.x;   // < 16384
    int n = idx >> 7, k = idx & 127;
    float s = 0.f;
    for (int j = 0; j < 128; j++) s += mW3[k * 128 + j] * nW0[(256 + j) * 128 + n];
    Ft[n * 128 + k] = (bf16_t)s;
}

// bfix[n] = nb0[n] + 20 * (mb3 @ nW0c)[n]
__global__ __launch_bounds__(128) void k_bias(const float* __restrict__ nb0, const float* __restrict__ mb3,
                                              const float* __restrict__ nW0, float* __restrict__ bfix) {
    int n = threadIdx.x;
    float s = 0.f;
    for (int j = 0; j < 128; j++) s += mb3[j] * nW0[(256 + j) * 128 + n];
    bfix[n] = nb0[n] + 20.f * s;
}

template <bool BF16OUT>
__global__ __launch_bounds__(256, 2) void k_simple_gemm(const float* __restrict__ in,
                                                        const bf16_t* __restrict__ Wt,
                                                        const float* __restrict__ bias,
                                                        void* __restrict__ out) {
    __shared__ __align__(16) char smem[65536];
    bf16_t* act = (bf16_t*)smem;
    bf16_t* wsm = (bf16_t*)(smem + 32768);
    int tid = threadIdx.x;
    size_t i0 = (size_t)blockIdx.x * 128;
    int lane = tid & 63, wid = tid >> 6;
    int wm = wid >> 1, wn = wid & 1, lrow = lane & 15, q = lane >> 4;

    stage_act_f32(act, in + i0 * 128, tid);
    stage_w(wsm, Wt, tid);
    __syncthreads();
    f32x4 acc[4][4];
    gemm128<false>(acc, act, wsm, wm, wn, lrow, q, true);
    #pragma unroll
    for (int nt = 0; nt < 4; nt++) {
        int col = wn * 64 + nt * 16 + lrow;
        float bb = bias ? bias[col] : 0.f;
        #pragma unroll
        for (int mt = 0; mt < 4; mt++)
            #pragma unroll
            for (int r = 0; r < 4; r++) {
                int row = wm * 64 + mt * 16 + q * 4 + r;
                float v = acc[mt][nt][r] + bb;
                if (BF16OUT) ((bf16_t*)out)[(i0 + row) * 128 + col] = (bf16_t)v;
                else         ((float*)out)[(i0 + row) * 128 + col] = v;
            }
    }
}

// ---------------- edge (message) kernel ----------------
// tile: 1 batch x 120 edges (6 dst nodes). Edge MLP layers 1,2 only; final linear
// layer folded into node kernel via SA = sum_{20 edges} act2 (per dst node).
__global__ __launch_bounds__(256, 2) void k_edge(const bf16_t* __restrict__ P, const bf16_t* __restrict__ Q,
                                                 const int* __restrict__ src, const bf16_t* __restrict__ Wb,
                                                 const float* __restrict__ mb0, const float* __restrict__ mb1,
                                                 const float* __restrict__ mb2, bf16_t* __restrict__ SA) {
    __shared__ __align__(16) char smem[65536];
    bf16_t* act = (bf16_t*)smem;
    bf16_t* wsm = (bf16_t*)(smem + 32768);
    int tid = threadIdx.x;
    int g = blockIdx.x, b = blockIdx.y;
    int e0 = g * 120, n0 = g * 6;
    int nreal = (e0 + 120 <= EE) ? 120 : (EE - e0);   // 120 or 60
    int lane = tid & 63, wid = tid >> 6;
    int wm = wid >> 1, wn = wid & 1, lrow = lane & 15, q = lane >> 4;

    float4 b1[4], b2[4];
    #pragma unroll
    for (int nt = 0; nt < 4; nt++) {
        b1[nt] = *(const float4*)&mb1[wn * 64 + nt * 16 + q * 4];
        b2[nt] = *(const float4*)&mb2[wn * 64 + nt * 16 + q * 4];
    }

    // layer-0: act0 = relu(P[src] + Q[dst] + mb0), staged as bf16 (rows >= nreal zeroed)
    for (int ch = tid; ch < 2048; ch += 256) {
        int r = ch >> 4, p = ch & 15;
        bf16x8 o;
        if (r < nreal) {
            int e = e0 + r;
            int sn = src[e];
            int dn = n0 + r / 20;
            bf16x8 pv = *(const bf16x8*)(P + ((size_t)b * NN + sn) * 128 + p * 8);
            bf16x8 qv = *(const bf16x8*)(Q + ((size_t)b * NN + dn) * 128 + p * 8);
            #pragma unroll
            for (int i = 0; i < 8; i++) {
                float t = (float)pv[i] + (float)qv[i] + mb0[p * 8 + i];
                o[i] = (bf16_t)fmaxf(t, 0.f);
            }
        } else {
            #pragma unroll
            for (int i = 0; i < 8; i++) o[i] = (bf16_t)0.f;
        }
        *(bf16x8*)&act[swz(r, p << 3)] = o;
    }
    stage_w(wsm, Wb + 2 * 16384, tid);          // mW1t
    __syncthreads();

    f32x4 acc[4][4];
    gemm128<true>(acc, act, wsm, wm, wn, lrow, q, true);
    __syncthreads();
    wb_swap(act, acc, b1, wm, wn, lrow, q);     // act1 = relu(.)
    stage_w(wsm, Wb + 3 * 16384, tid);          // mW2t
    __syncthreads();
    gemm128<true>(acc, act, wsm, wm, wn, lrow, q, true);
    __syncthreads();
    wb_swap(act, acc, b2, wm, wn, lrow, q);     // act2 = relu(.)
    __syncthreads();

    // SA[b][n0+j][c] = sum over the node's 20 edges of act2 (f32 accumulate)
    int nodes = nreal / 20;
    for (int o = tid; o < 768; o += 256) {
        int j = o >> 7, c = o & 127;
        if (j < nodes) {
            float s = 0.f;
            #pragma unroll
            for (int i = 0; i < 20; i++) s += (float)act[swz(20 * j + i, c)];
            SA[((size_t)b * NN + n0 + j) * 128 + c] = (bf16_t)s;
        }
    }
}

// ---------------- node kernel: node MLP + residual + LN + next-step P/Q ----------------
__global__ __launch_bounds__(256, 2) void k_node(float* __restrict__ h, const bf16_t* __restrict__ SA,
                                                 const float* __restrict__ C2, const bf16_t* __restrict__ Wb,
                                                 const float* __restrict__ nb1, const float* __restrict__ nb2,
                                                 const float* __restrict__ nb3, const float* __restrict__ ln_g,
                                                 const float* __restrict__ ln_b,
                                                 bf16_t* __restrict__ Pd, bf16_t* __restrict__ Qd) {
    __shared__ __align__(16) char smem[65536];
    bf16_t* act = (bf16_t*)smem;
    bf16_t* wsm = (bf16_t*)(smem + 32768);
    float*  st  = (float*)(smem + 32768);       // 128 rows x {s1,s2} x 2 halves
    int tid = threadIdx.x;
    size_t i0 = (size_t)blockIdx.x * 128;
    int lane = tid & 63, wid = tid >> 6;
    int wm = wid >> 1, wn = wid & 1, lrow = lane & 15, q = lane >> 4;

    f32x4 acc[4][4];
    stage_act_f32(act, h + i0 * 128, tid);
    stage_w(wsm, Wb + 5 * 16384, tid);          // nW0at (h part)
    __syncthreads();
    gemm128<false>(acc, act, wsm, wm, wn, lrow, q, true);
    __syncthreads();
    stage_act_bf16(act, SA + i0 * 128, tid);
    stage_w(wsm, Wb + 11 * 16384, tid);         // Ft = (mW3 @ nW0c)^T
    __syncthreads();
    gemm128<false>(acc, act, wsm, wm, wn, lrow, q, false);   // accumulate
    __syncthreads();
    // u0 = relu(acc + C2)   (C2 = x_embed@nW0b + nb0 + 20*mb3@nW0c, precomputed)
    #pragma unroll
    for (int nt = 0; nt < 4; nt++) {
        int col = wn * 64 + nt * 16 + lrow;
        #pragma unroll
        for (int mt = 0; mt < 4; mt++)
            #pragma unroll
            for (int r = 0; r < 4; r++) {
                int row = wm * 64 + mt * 16 + q * 4 + r;
                float v = acc[mt][nt][r] + C2[(i0 + row) * 128 + col];
                act[swz(row, col)] = (bf16_t)fmaxf(v, 0.f);
            }
    }
    stage_w(wsm, Wb + 7 * 16384, tid);          // nW1t
    __syncthreads();
    gemm128<false>(acc, act, wsm, wm, wn, lrow, q, true);
    __syncthreads();
    writeback(act, acc, nb1, wm, wn, lrow, q, true);
    stage_w(wsm, Wb + 8 * 16384, tid);          // nW2t
    __syncthreads();
    gemm128<false>(acc, act, wsm, wm, wn, lrow, q, true);
    __syncthreads();
    writeback(act, acc, nb2, wm, wn, lrow, q, true);
    stage_w(wsm, Wb + 9 * 16384, tid);          // nW3t
    __syncthreads();
    gemm128<false>(acc, act, wsm, wm, wn, lrow, q, true);
    __syncthreads();

    // v = u3 + nb3 + h  (residual), accumulate LN stats
    float s1[4][4], s2[4][4];
    #pragma unroll
    for (int mt = 0; mt < 4; mt++)
        #pragma unroll
        for (int r = 0; r < 4; r++) { s1[mt][r] = 0.f; s2[mt][r] = 0.f; }
    #pragma unroll
    for (int nt = 0; nt < 4; nt++) {
        int col = wn * 64 + nt * 16 + lrow;
        float bb = nb3[col];
        #pragma unroll
        for (int mt = 0; mt < 4; mt++)
            #pragma unroll
            for (int r = 0; r < 4; r++) {
                int row = wm * 64 + mt * 16 + q * 4 + r;
                float v = acc[mt][nt][r] + bb + h[(i0 + row) * 128 + col];
                acc[mt][nt][r] = v;
                s1[mt][r] += v;
                s2[mt][r] += v * v;
            }
    }
    #pragma unroll
    for (int mt = 0; mt < 4; mt++)
        #pragma unroll
        for (int r = 0; r < 4; r++) {
            float a = s1[mt][r], b2 = s2[mt][r];
            #pragma unroll
            for (int off = 1; off < 16; off <<= 1) {
                a  += __shfl_xor(a, off);
                b2 += __shfl_xor(b2, off);
            }
            s1[mt][r] = a; s2[mt][r] = b2;
        }
    if (lrow == 0) {
        #pragma unroll
        for (int mt = 0; mt < 4; mt++)
            #pragma unroll
            for (int r = 0; r < 4; r++) {
                int row = wm * 64 + mt * 16 + q * 4 + r;
                st[row * 4 + wn * 2 + 0] = s1[mt][r];
                st[row * 4 + wn * 2 + 1] = s2[mt][r];
            }
    }
    __syncthreads();
    float mu[4][4], rs[4][4];
    #pragma unroll
    for (int mt = 0; mt < 4; mt++)
        #pragma unroll
        for (int r = 0; r < 4; r++) {
            int row = wm * 64 + mt * 16 + q * 4 + r;
            float m  = (st[row * 4 + 0] + st[row * 4 + 2]) * (1.f / 128.f);
            float m2 = (st[row * 4 + 1] + st[row * 4 + 3]) * (1.f / 128.f);
            mu[mt][r] = m;
            rs[mt][r] = rsqrtf(m2 - m * m + 1e-5f);
        }
    // apply LN: h (f32 global) + act (bf16 LDS for P/Q GEMM)
    #pragma unroll
    for (int nt = 0; nt < 4; nt++) {
        int col = wn * 64 + nt * 16 + lrow;
        float gg = ln_g[col], bb = ln_b[col];
        #pragma unroll
        for (int mt = 0; mt < 4; mt++)
            #pragma unroll
            for (int r = 0; r < 4; r++) {
                int row = wm * 64 + mt * 16 + q * 4 + r;
                float hn = (acc[mt][nt][r] - mu[mt][r]) * rs[mt][r] * gg + bb;
                h[(i0 + row) * 128 + col] = hn;
                act[swz(row, col)] = (bf16_t)hn;
            }
    }
    __syncthreads();
    stage_w(wsm, Wb + 0 * 16384, tid);          // mW0at
    __syncthreads();
    gemm128<false>(acc, act, wsm, wm, wn, lrow, q, true);
    #pragma unroll
    for (int nt = 0; nt < 4; nt++) {
        int col = wn * 64 + nt * 16 + lrow;
        #pragma unroll
        for (int mt = 0; mt < 4; mt++)
            #pragma unroll
            for (int r = 0; r < 4; r++) {
                int row = wm * 64 + mt * 16 + q * 4 + r;
                Pd[(i0 + row) * 128 + col] = (bf16_t)acc[mt][nt][r];
            }
    }
    __syncthreads();
    stage_w(wsm, Wb + 1 * 16384, tid);          // mW0bt
    __syncthreads();
    gemm128<false>(acc, act, wsm, wm, wn, lrow, q, true);
    #pragma unroll
    for (int nt = 0; nt < 4; nt++) {
        int col = wn * 64 + nt * 16 + lrow;
        #pragma unroll
        for (int mt = 0; mt < 4; mt++)
            #pragma unroll
            for (int r = 0; r < 4; r++) {
                int row = wm * 64 + mt * 16 + q * 4 + r;
                Qd[(i0 + row) * 128 + col] = (bf16_t)acc[mt][nt][r];
            }
    }
}

__global__ __launch_bounds__(256) void k_out(const float* __restrict__ h, const float* __restrict__ W_out,
                                             const float* __restrict__ b_out, float* __restrict__ out) {
    int idx = blockIdx.x * 256 + threadIdx.x;   // < BN*9
    int row = idx / 9, o = idx - row * 9;
    const float* hr = h + (size_t)row * 128;
    float s = b_out[o];
    #pragma unroll 4
    for (int k = 0; k < 128; k++) s += hr[k] * W_out[k * 9 + o];
    out[idx] = s;
}

extern "C" void kernel_launch(void* const* d_in, const int* in_sizes, int n_in,
                              void* d_out, int out_size, void* d_ws, size_t ws_size,
                              hipStream_t stream) {
    const float* x    = (const float*)d_in[0];
    const int*   src  = (const int*)d_in[1];
    const float* W_in = (const float*)d_in[3];
    const float* b_in = (const float*)d_in[4];
    const float* pos  = (const float*)d_in[5];
    const float* mW0  = (const float*)d_in[6];
    const float* mb0  = (const float*)d_in[7];
    const float* mW1  = (const float*)d_in[8];
    const float* mb1  = (const float*)d_in[9];
    const float* mW2  = (const float*)d_in[10];
    const float* mb2  = (const float*)d_in[11];
    const float* mW3  = (const float*)d_in[12];
    const float* mb3  = (const float*)d_in[13];
    const float* nW0  = (const float*)d_in[14];
    const float* nb0  = (const float*)d_in[15];
    const float* nW1  = (const float*)d_in[16];
    const float* nb1  = (const float*)d_in[17];
    const float* nW2  = (const float*)d_in[18];
    const float* nb2  = (const float*)d_in[19];
    const float* nW3  = (const float*)d_in[20];
    const float* nb3  = (const float*)d_in[21];
    const float* ln_g = (const float*)d_in[22];
    const float* ln_b = (const float*)d_in[23];
    const float* W_out= (const float*)d_in[24];
    const float* b_out= (const float*)d_in[25];

    char* ws = (char*)d_ws;
    float*  h   = (float*)ws;                       // 21,233,664 B (also x_embed)
    float*  C2  = (float*)(ws + 21233664);          // 21,233,664 B
    bf16_t* SA  = (bf16_t*)(ws + 42467328);         // 10,616,832 B (summed act2 per node)
    bf16_t* P   = (bf16_t*)(ws + 53084160);         // 10,616,832 B
    bf16_t* Q   = (bf16_t*)(ws + 63700992);         // 10,616,832 B
    bf16_t* Wb  = (bf16_t*)(ws + 74317824);         // 12 * 32,768 B (bf16, transposed)
    float*  bfix= (float*)(ws + 74711040);          // 512 B

    k_embed<<<20736, 256, 0, stream>>>(x, W_in, b_in, pos, h);

    // transposed bf16 weights: [0]mW0a [1]mW0b [2]mW1 [3]mW2 [4]mW3(unused)
    //                          [5]nW0a(h) [6]nW0c(agg,unused) [7]nW1 [8]nW2 [9]nW3
    //                          [10]nW0b(x) [11]Ft=(mW3@nW0c)^T
    const float* tsrc[11] = {mW0, mW0 + 16384, mW1, mW2, mW3,
                             nW0, nW0 + 32768, nW1, nW2, nW3, nW0 + 16384};
    for (int i = 0; i < 11; i++)
        k_transpose<<<64, 256, 0, stream>>>(tsrc[i], Wb + i * 16384);
    k_fuse<<<64, 256, 0, stream>>>(mW3, nW0, Wb + 11 * 16384);
    k_bias<<<1, 128, 0, stream>>>(nb0, mb3, nW0, bfix);

    k_simple_gemm<false><<<324, 256, 0, stream>>>(h, Wb + 10 * 16384, bfix, C2);  // C2
    k_simple_gemm<true ><<<324, 256, 0, stream>>>(h, Wb + 0 * 16384, nullptr, P); // P0
    k_simple_gemm<true ><<<324, 256, 0, stream>>>(h, Wb + 1 * 16384, nullptr, Q); // Q0

    for (int s = 0; s < 16; s++) {
        k_edge<<<dim3(14, 512), 256, 0, stream>>>(P, Q, src, Wb, mb0, mb1, mb2, SA);
        k_node<<<324, 256, 0, stream>>>(h, SA, C2, Wb, nb1, nb2, nb3, ln_g, ln_b, P, Q);
    }
    k_out<<<1458, 256, 0, stream>>>(h, W_out, b_out, (float*)d_out);
}

// Round 3
// 2612.956 us; speedup vs baseline: 1.8496x; 1.4872x over previous
//
#include <hip/hip_runtime.h>

typedef __bf16 bf16_t;
typedef bf16_t bf16x8 __attribute__((ext_vector_type(8)));
typedef bf16_t bf16x4 __attribute__((ext_vector_type(4)));
typedef float  f32x4  __attribute__((ext_vector_type(4)));

#define NN   81
#define BB   512
#define BN   41472          // 512*81
#define EE   1620

// element-index swizzle for 128-wide rows of 2B elements: keeps 8-elem groups
// contiguous (16B vector ops), conflict profile ~= +8 padding
__device__ __forceinline__ int swz(int r, int k) {
    return (r << 7) + ((((k >> 3) ^ (r & 7)) << 3) | (k & 7));
}

// packed-weight element offset for W'[n][k] (128x128): fragment-ordered so that
// lane (q*16+lrow) reads its mfma fragment as ONE coalesced 16B global load.
// po = wn*8192 + f*512 + lane*8 + e;  wn=n>>6, f=(k>>5)*4+((n>>4)&3),
// lane=((k>>3)&3)*16+(n&15), e=k&7
__device__ __forceinline__ int wpack(int n, int k) {
    return ((n >> 6) << 13) + (((((k >> 5) << 2) + ((n >> 4) & 3))) << 9)
         + (((((k >> 3) & 3) << 4) + (n & 15)) << 3) + (k & 7);
}

// stage 128 rows of f32 (stride 128) -> bf16 LDS
__device__ __forceinline__ void stage_act_f32(bf16_t* act, const float* __restrict__ src, int tid) {
    for (int ch = tid; ch < 2048; ch += 256) {
        int r = ch >> 4, p = ch & 15;
        const float4 a = *(const float4*)(src + (size_t)r * 128 + p * 8);
        const float4 b = *(const float4*)(src + (size_t)r * 128 + p * 8 + 4);
        bf16x8 o;
        o[0] = (bf16_t)a.x; o[1] = (bf16_t)a.y; o[2] = (bf16_t)a.z; o[3] = (bf16_t)a.w;
        o[4] = (bf16_t)b.x; o[5] = (bf16_t)b.y; o[6] = (bf16_t)b.z; o[7] = (bf16_t)b.w;
        *(bf16x8*)&act[swz(r, p << 3)] = o;
    }
}

// 128x128x128 GEMM, swapped output: acc[nt][mt] = D[n][m],
// n = wn*64+nt*16+q*4+r (feature), m = wm*64+mt*16+lrow (row).
// Weights come straight from packed global (L1/L2-hot), act from LDS.
__device__ __forceinline__ void gemm128s(f32x4 (&acc)[4][4], const bf16_t* act,
                                         const bf16_t* __restrict__ Wp,
                                         int wm, int wn, int lane, int lrow, int q, bool zero) {
    if (zero) {
        f32x4 z = {0.f, 0.f, 0.f, 0.f};
        #pragma unroll
        for (int i = 0; i < 4; i++)
            #pragma unroll
            for (int j = 0; j < 4; j++) acc[i][j] = z;
    }
    const bf16_t* wbase = Wp + (wn << 13) + (lane << 3);
    #pragma unroll
    for (int k0 = 0; k0 < 128; k0 += 32) {
        bf16x8 af[4], wf[4];
        #pragma unroll
        for (int mt = 0; mt < 4; mt++)
            af[mt] = *(const bf16x8*)&act[swz(wm * 64 + mt * 16 + lrow, k0 + q * 8)];
        #pragma unroll
        for (int nt = 0; nt < 4; nt++)
            wf[nt] = *(const bf16x8*)(wbase + ((((k0 >> 5) << 2) + nt) << 9));
        #pragma unroll
        for (int nt = 0; nt < 4; nt++)
            #pragma unroll
            for (int mt = 0; mt < 4; mt++)
                acc[nt][mt] = __builtin_amdgcn_mfma_f32_16x16x32_bf16(wf[nt], af[mt], acc[nt][mt], 0, 0, 0);
    }
}

// swapped writeback to LDS: act[m][n..n+3] <- relu(acc + bias), 8B packed stores
__device__ __forceinline__ void wb_swap(bf16_t* act, f32x4 (&acc)[4][4], const float4 (&bias)[4],
                                        int wm, int wn, int lrow, int q) {
    #pragma unroll
    for (int nt = 0; nt < 4; nt++) {
        int nb = wn * 64 + nt * 16 + q * 4;
        #pragma unroll
        for (int mt = 0; mt < 4; mt++) {
            int m = wm * 64 + mt * 16 + lrow;
            bf16x4 o;
            o[0] = (bf16_t)fmaxf(acc[nt][mt][0] + bias[nt].x, 0.f);
            o[1] = (bf16_t)fmaxf(acc[nt][mt][1] + bias[nt].y, 0.f);
            o[2] = (bf16_t)fmaxf(acc[nt][mt][2] + bias[nt].z, 0.f);
            o[3] = (bf16_t)fmaxf(acc[nt][mt][3] + bias[nt].w, 0.f);
            *(bf16x4*)&act[swz(m, nb)] = o;
        }
    }
}

// ---------------- prep kernels ----------------

__global__ __launch_bounds__(256) void k_embed(const float* __restrict__ x, const float* __restrict__ W_in,
                                               const float* __restrict__ b_in, const float* __restrict__ pos,
                                               float* __restrict__ h) {
    int idx = blockIdx.x * 256 + threadIdx.x;   // < BN*128
    int row = idx >> 7, col = idx & 127;
    int n = row % NN;
    const float* xr = x + (size_t)row * 10;
    float s = b_in[col] + pos[n * 128 + col];
    #pragma unroll
    for (int k = 0; k < 10; k++) s += xr[k] * W_in[k * 128 + col];
    h[idx] = s;
}

// pack plain f32 W[k][n] (128x128) -> fragment-ordered bf16
__global__ __launch_bounds__(256) void k_pack(const float* __restrict__ src, bf16_t* __restrict__ dst) {
    int idx = blockIdx.x * 256 + threadIdx.x;   // < 16384
    int n = idx >> 7, k = idx & 127;
    dst[wpack(n, k)] = (bf16_t)src[k * 128 + n];
}

// Ft = mW3 @ nW0c fused weight, written packed (slot 5)
__global__ __launch_bounds__(256) void k_fuse(const float* __restrict__ mW3, const float* __restrict__ nW0,
                                              bf16_t* __restrict__ Ft) {
    int idx = blockIdx.x * 256 + threadIdx.x;   // < 16384
    int n = idx >> 7, k = idx & 127;
    float s = 0.f;
    for (int j = 0; j < 128; j++) s += mW3[k * 128 + j] * nW0[(256 + j) * 128 + n];
    Ft[wpack(n, k)] = (bf16_t)s;
}

// bfix[n] = nb0[n] + 20 * (mb3 @ nW0c)[n]
__global__ __launch_bounds__(128) void k_bias(const float* __restrict__ nb0, const float* __restrict__ mb3,
                                              const float* __restrict__ nW0, float* __restrict__ bfix) {
    int n = threadIdx.x;
    float s = 0.f;
    for (int j = 0; j < 128; j++) s += mb3[j] * nW0[(256 + j) * 128 + n];
    bfix[n] = nb0[n] + 20.f * s;
}

template <bool BF16OUT>
__global__ __launch_bounds__(256, 2) void k_simple_gemm(const float* __restrict__ in,
                                                        const bf16_t* __restrict__ Wp,
                                                        const float* __restrict__ bias,
                                                        void* __restrict__ out) {
    __shared__ __align__(16) bf16_t act[16384];
    int tid = threadIdx.x;
    size_t i0 = (size_t)blockIdx.x * 128;
    int lane = tid & 63, wid = tid >> 6;
    int wm = wid >> 1, wn = wid & 1, lrow = lane & 15, q = lane >> 4;

    stage_act_f32(act, in + i0 * 128, tid);
    __syncthreads();
    f32x4 acc[4][4];
    gemm128s(acc, act, Wp, wm, wn, lane, lrow, q, true);
    #pragma unroll
    for (int nt = 0; nt < 4; nt++) {
        int nb = wn * 64 + nt * 16 + q * 4;
        float4 b4 = bias ? *(const float4*)&bias[nb] : make_float4(0.f, 0.f, 0.f, 0.f);
        #pragma unroll
        for (int mt = 0; mt < 4; mt++) {
            int m = wm * 64 + mt * 16 + lrow;
            if (BF16OUT) {
                bf16x4 o;
                o[0] = (bf16_t)(acc[nt][mt][0] + b4.x);
                o[1] = (bf16_t)(acc[nt][mt][1] + b4.y);
                o[2] = (bf16_t)(acc[nt][mt][2] + b4.z);
                o[3] = (bf16_t)(acc[nt][mt][3] + b4.w);
                *(bf16x4*)((bf16_t*)out + (i0 + m) * 128 + nb) = o;
            } else {
                float4 o;
                o.x = acc[nt][mt][0] + b4.x; o.y = acc[nt][mt][1] + b4.y;
                o.z = acc[nt][mt][2] + b4.z; o.w = acc[nt][mt][3] + b4.w;
                *(float4*)((float*)out + (i0 + m) * 128 + nb) = o;
            }
        }
    }
}

// ---------------- edge (message) kernel ----------------
// tile: 1 batch x 120 edges (6 dst nodes). Layers 1,2 of the edge MLP; layer 3
// folded into node kernel via SA = sum_{20 edges} act2.
__global__ __launch_bounds__(256, 3) void k_edge(const bf16_t* __restrict__ P, const bf16_t* __restrict__ Q,
                                                 const int* __restrict__ src, const bf16_t* __restrict__ Wp,
                                                 const float* __restrict__ mb0, const float* __restrict__ mb1,
                                                 const float* __restrict__ mb2, bf16_t* __restrict__ SA) {
    __shared__ __align__(16) bf16_t act[16384];
    int tid = threadIdx.x;
    int g = blockIdx.x, b = blockIdx.y;
    int e0 = g * 120, n0 = g * 6;
    int nreal = (e0 + 120 <= EE) ? 120 : (EE - e0);   // 120 or 60
    int lane = tid & 63, wid = tid >> 6;
    int wm = wid >> 1, wn = wid & 1, lrow = lane & 15, q = lane >> 4;

    float4 b1[4], b2[4];
    #pragma unroll
    for (int nt = 0; nt < 4; nt++) {
        b1[nt] = *(const float4*)&mb1[wn * 64 + nt * 16 + q * 4];
        b2[nt] = *(const float4*)&mb2[wn * 64 + nt * 16 + q * 4];
    }

    // layer-0: act0 = relu(P[src] + Q[dst] + mb0), rows >= nreal zeroed
    for (int ch = tid; ch < 2048; ch += 256) {
        int r = ch >> 4, p = ch & 15;
        bf16x8 o;
        if (r < nreal) {
            int e = e0 + r;
            int sn = src[e];
            int dn = n0 + r / 20;
            bf16x8 pv = *(const bf16x8*)(P + (((size_t)b * NN + sn) << 7) + (p << 3));
            bf16x8 qv = *(const bf16x8*)(Q + (((size_t)b * NN + dn) << 7) + (p << 3));
            float4 m0a = *(const float4*)&mb0[p * 8];
            float4 m0b = *(const float4*)&mb0[p * 8 + 4];
            o[0] = (bf16_t)fmaxf((float)pv[0] + (float)qv[0] + m0a.x, 0.f);
            o[1] = (bf16_t)fmaxf((float)pv[1] + (float)qv[1] + m0a.y, 0.f);
            o[2] = (bf16_t)fmaxf((float)pv[2] + (float)qv[2] + m0a.z, 0.f);
            o[3] = (bf16_t)fmaxf((float)pv[3] + (float)qv[3] + m0a.w, 0.f);
            o[4] = (bf16_t)fmaxf((float)pv[4] + (float)qv[4] + m0b.x, 0.f);
            o[5] = (bf16_t)fmaxf((float)pv[5] + (float)qv[5] + m0b.y, 0.f);
            o[6] = (bf16_t)fmaxf((float)pv[6] + (float)qv[6] + m0b.z, 0.f);
            o[7] = (bf16_t)fmaxf((float)pv[7] + (float)qv[7] + m0b.w, 0.f);
        } else {
            #pragma unroll
            for (int i = 0; i < 8; i++) o[i] = (bf16_t)0.f;
        }
        *(bf16x8*)&act[swz(r, p << 3)] = o;
    }
    __syncthreads();

    f32x4 acc[4][4];
    gemm128s(acc, act, Wp + 2 * 16384, wm, wn, lane, lrow, q, true);
    __syncthreads();
    wb_swap(act, acc, b1, wm, wn, lrow, q);     // act1
    __syncthreads();
    gemm128s(acc, act, Wp + 3 * 16384, wm, wn, lane, lrow, q, true);
    __syncthreads();
    wb_swap(act, acc, b2, wm, wn, lrow, q);     // act2
    __syncthreads();

    // SA[b][n0+j][c] = sum of act2 over the node's 20 edges (vectorized, 2-thread split)
    if (tid < 192) {
        int j = tid >> 5;              // node 0..5
        int sub = tid & 31;
        int rr = sub >> 1;             // 8-feature chunk 0..15
        int half = sub & 1;
        int nodes = nreal / 20;
        if (j < nodes) {
            float s0 = 0.f, s1 = 0.f, s2 = 0.f, s3 = 0.f, s4 = 0.f, s5 = 0.f, s6 = 0.f, s7 = 0.f;
            #pragma unroll
            for (int i = 0; i < 10; i++) {
                int m = 20 * j + half * 10 + i;
                bf16x8 v = *(const bf16x8*)&act[swz(m, rr << 3)];
                s0 += (float)v[0]; s1 += (float)v[1]; s2 += (float)v[2]; s3 += (float)v[3];
                s4 += (float)v[4]; s5 += (float)v[5]; s6 += (float)v[6]; s7 += (float)v[7];
            }
            s0 += __shfl_xor(s0, 1); s1 += __shfl_xor(s1, 1);
            s2 += __shfl_xor(s2, 1); s3 += __shfl_xor(s3, 1);
            s4 += __shfl_xor(s4, 1); s5 += __shfl_xor(s5, 1);
            s6 += __shfl_xor(s6, 1); s7 += __shfl_xor(s7, 1);
            if (half == 0) {
                bf16x8 o;
                o[0] = (bf16_t)s0; o[1] = (bf16_t)s1; o[2] = (bf16_t)s2; o[3] = (bf16_t)s3;
                o[4] = (bf16_t)s4; o[5] = (bf16_t)s5; o[6] = (bf16_t)s6; o[7] = (bf16_t)s7;
                *(bf16x8*)(SA + (((size_t)b * NN + n0 + j) << 7) + (rr << 3)) = o;
            }
        }
    }
}

// ---------------- node kernel: M=32 tiles, wave tile 32x32, swapped layout ----------------
__device__ __forceinline__ void gemm32s(f32x4 (&acc)[2][2], const bf16_t* act,
                                        const bf16_t* __restrict__ Wp,
                                        int wid, int lane, int lrow, int q, bool zero) {
    if (zero) {
        f32x4 z = {0.f, 0.f, 0.f, 0.f};
        acc[0][0] = z; acc[0][1] = z; acc[1][0] = z; acc[1][1] = z;
    }
    int wn = wid >> 1, ntb = (wid & 1) << 1;
    const bf16_t* wbase = Wp + (wn << 13) + (lane << 3);
    #pragma unroll
    for (int k0 = 0; k0 < 128; k0 += 32) {
        bf16x8 af[2], wf[2];
        af[0] = *(const bf16x8*)&act[swz(lrow, k0 + q * 8)];
        af[1] = *(const bf16x8*)&act[swz(16 + lrow, k0 + q * 8)];
        wf[0] = *(const bf16x8*)(wbase + ((((k0 >> 5) << 2) + ntb) << 9));
        wf[1] = *(const bf16x8*)(wbase + ((((k0 >> 5) << 2) + ntb + 1) << 9));
        #pragma unroll
        for (int nt = 0; nt < 2; nt++)
            #pragma unroll
            for (int mt = 0; mt < 2; mt++)
                acc[nt][mt] = __builtin_amdgcn_mfma_f32_16x16x32_bf16(wf[nt], af[mt], acc[nt][mt], 0, 0, 0);
    }
}

__device__ __forceinline__ void wb32(bf16_t* act, f32x4 (&acc)[2][2], const float* __restrict__ bias,
                                     int colb, int lrow, int q) {
    #pragma unroll
    for (int nt = 0; nt < 2; nt++) {
        int nb = colb + nt * 16 + q * 4;
        float4 b4 = *(const float4*)&bias[nb];
        #pragma unroll
        for (int mt = 0; mt < 2; mt++) {
            int m = mt * 16 + lrow;
            bf16x4 o;
            o[0] = (bf16_t)fmaxf(acc[nt][mt][0] + b4.x, 0.f);
            o[1] = (bf16_t)fmaxf(acc[nt][mt][1] + b4.y, 0.f);
            o[2] = (bf16_t)fmaxf(acc[nt][mt][2] + b4.z, 0.f);
            o[3] = (bf16_t)fmaxf(acc[nt][mt][3] + b4.w, 0.f);
            *(bf16x4*)&act[swz(m, nb)] = o;
        }
    }
}

__global__ __launch_bounds__(256, 4) void k_node(float* __restrict__ h, const bf16_t* __restrict__ SA,
                                                 const float* __restrict__ C2, const bf16_t* __restrict__ Wp,
                                                 const float* __restrict__ nb1, const float* __restrict__ nb2,
                                                 const float* __restrict__ nb3, const float* __restrict__ ln_g,
                                                 const float* __restrict__ ln_b,
                                                 bf16_t* __restrict__ Pd, bf16_t* __restrict__ Qd) {
    __shared__ __align__(16) bf16_t act[4096];   // 32 rows x 128
    __shared__ float st[256];                    // 32 rows x 4 waves x {s1,s2}
    int tid = threadIdx.x;
    size_t i0 = (size_t)blockIdx.x * 32;
    int lane = tid & 63, wid = tid >> 6;
    int lrow = lane & 15, q = lane >> 4;
    int colb = wid * 32;

    // stage h rows (f32 -> bf16)
    for (int ch = tid; ch < 512; ch += 256) {
        int r = ch >> 4, p = ch & 15;
        const float4 a = *(const float4*)(h + (i0 + r) * 128 + (p << 3));
        const float4 c = *(const float4*)(h + (i0 + r) * 128 + (p << 3) + 4);
        bf16x8 o;
        o[0] = (bf16_t)a.x; o[1] = (bf16_t)a.y; o[2] = (bf16_t)a.z; o[3] = (bf16_t)a.w;
        o[4] = (bf16_t)c.x; o[5] = (bf16_t)c.y; o[6] = (bf16_t)c.z; o[7] = (bf16_t)c.w;
        *(bf16x8*)&act[swz(r, p << 3)] = o;
    }
    __syncthreads();
    f32x4 acc[2][2];
    gemm32s(acc, act, Wp + 4 * 16384, wid, lane, lrow, q, true);     // h @ nW0a
    __syncthreads();
    for (int ch = tid; ch < 512; ch += 256) {                        // stage SA
        int r = ch >> 4, p = ch & 15;
        *(bf16x8*)&act[swz(r, p << 3)] = *(const bf16x8*)(SA + (i0 + r) * 128 + (p << 3));
    }
    __syncthreads();
    gemm32s(acc, act, Wp + 5 * 16384, wid, lane, lrow, q, false);    // + SA @ Ft
    __syncthreads();
    // u0 = relu(acc + C2)
    #pragma unroll
    for (int nt = 0; nt < 2; nt++) {
        int nb = colb + nt * 16 + q * 4;
        #pragma unroll
        for (int mt = 0; mt < 2; mt++) {
            int m = mt * 16 + lrow;
            float4 c4 = *(const float4*)(C2 + (i0 + m) * 128 + nb);
            bf16x4 o;
            o[0] = (bf16_t)fmaxf(acc[nt][mt][0] + c4.x, 0.f);
            o[1] = (bf16_t)fmaxf(acc[nt][mt][1] + c4.y, 0.f);
            o[2] = (bf16_t)fmaxf(acc[nt][mt][2] + c4.z, 0.f);
            o[3] = (bf16_t)fmaxf(acc[nt][mt][3] + c4.w, 0.f);
            *(bf16x4*)&act[swz(m, nb)] = o;
        }
    }
    __syncthreads();
    gemm32s(acc, act, Wp + 6 * 16384, wid, lane, lrow, q, true);     // nW1
    __syncthreads();
    wb32(act, acc, nb1, colb, lrow, q);
    __syncthreads();
    gemm32s(acc, act, Wp + 7 * 16384, wid, lane, lrow, q, true);     // nW2
    __syncthreads();
    wb32(act, acc, nb2, colb, lrow, q);
    __syncthreads();
    gemm32s(acc, act, Wp + 8 * 16384, wid, lane, lrow, q, true);     // nW3

    // residual v = acc + nb3 + h, LN stats
    float s1[2] = {0.f, 0.f}, s2[2] = {0.f, 0.f};
    #pragma unroll
    for (int nt = 0; nt < 2; nt++) {
        int nb = colb + nt * 16 + q * 4;
        float4 b4 = *(const float4*)&nb3[nb];
        #pragma unroll
        for (int mt = 0; mt < 2; mt++) {
            int m = mt * 16 + lrow;
            float4 h4 = *(const float4*)(h + (i0 + m) * 128 + nb);
            float v0 = acc[nt][mt][0] + b4.x + h4.x;
            float v1 = acc[nt][mt][1] + b4.y + h4.y;
            float v2 = acc[nt][mt][2] + b4.z + h4.z;
            float v3 = acc[nt][mt][3] + b4.w + h4.w;
            acc[nt][mt][0] = v0; acc[nt][mt][1] = v1;
            acc[nt][mt][2] = v2; acc[nt][mt][3] = v3;
            s1[mt] += v0 + v1 + v2 + v3;
            s2[mt] += v0 * v0 + v1 * v1 + v2 * v2 + v3 * v3;
        }
    }
    #pragma unroll
    for (int mt = 0; mt < 2; mt++) {
        float a = s1[mt], c = s2[mt];
        a += __shfl_xor(a, 16); c += __shfl_xor(c, 16);
        a += __shfl_xor(a, 32); c += __shfl_xor(c, 32);
        s1[mt] = a; s2[mt] = c;
    }
    if (q == 0) {
        #pragma unroll
        for (int mt = 0; mt < 2; mt++) {
            st[(mt * 16 + lrow) * 8 + wid * 2 + 0] = s1[mt];
            st[(mt * 16 + lrow) * 8 + wid * 2 + 1] = s2[mt];
        }
    }
    __syncthreads();
    float mu[2], rs[2];
    #pragma unroll
    for (int mt = 0; mt < 2; mt++) {
        int m = mt * 16 + lrow;
        float a = st[m * 8 + 0] + st[m * 8 + 2] + st[m * 8 + 4] + st[m * 8 + 6];
        float c = st[m * 8 + 1] + st[m * 8 + 3] + st[m * 8 + 5] + st[m * 8 + 7];
        a *= (1.f / 128.f); c *= (1.f / 128.f);
        mu[mt] = a;
        rs[mt] = rsqrtf(c - a * a + 1e-5f);
    }
    // LN apply -> h (f32) and act (bf16, for P/Q gemms)
    #pragma unroll
    for (int nt = 0; nt < 2; nt++) {
        int nb = colb + nt * 16 + q * 4;
        float4 g4 = *(const float4*)&ln_g[nb];
        float4 bb4 = *(const float4*)&ln_b[nb];
        #pragma unroll
        for (int mt = 0; mt < 2; mt++) {
            int m = mt * 16 + lrow;
            float4 o4;
            o4.x = (acc[nt][mt][0] - mu[mt]) * rs[mt] * g4.x + bb4.x;
            o4.y = (acc[nt][mt][1] - mu[mt]) * rs[mt] * g4.y + bb4.y;
            o4.z = (acc[nt][mt][2] - mu[mt]) * rs[mt] * g4.z + bb4.z;
            o4.w = (acc[nt][mt][3] - mu[mt]) * rs[mt] * g4.w + bb4.w;
            *(float4*)(h + (i0 + m) * 128 + nb) = o4;
            bf16x4 ob;
            ob[0] = (bf16_t)o4.x; ob[1] = (bf16_t)o4.y;
            ob[2] = (bf16_t)o4.z; ob[3] = (bf16_t)o4.w;
            *(bf16x4*)&act[swz(m, nb)] = ob;
        }
    }
    __syncthreads();
    gemm32s(acc, act, Wp + 0 * 16384, wid, lane, lrow, q, true);     // mW0a -> P
    #pragma unroll
    for (int nt = 0; nt < 2; nt++) {
        int nb = colb + nt * 16 + q * 4;
        #pragma unroll
        for (int mt = 0; mt < 2; mt++) {
            int m = mt * 16 + lrow;
            bf16x4 o;
            o[0] = (bf16_t)acc[nt][mt][0]; o[1] = (bf16_t)acc[nt][mt][1];
            o[2] = (bf16_t)acc[nt][mt][2]; o[3] = (bf16_t)acc[nt][mt][3];
            *(bf16x4*)(Pd + (i0 + m) * 128 + nb) = o;
        }
    }
    gemm32s(acc, act, Wp + 1 * 16384, wid, lane, lrow, q, true);     // mW0b -> Q
    #pragma unroll
    for (int nt = 0; nt < 2; nt++) {
        int nb = colb + nt * 16 + q * 4;
        #pragma unroll
        for (int mt = 0; mt < 2; mt++) {
            int m = mt * 16 + lrow;
            bf16x4 o;
            o[0] = (bf16_t)acc[nt][mt][0]; o[1] = (bf16_t)acc[nt][mt][1];
            o[2] = (bf16_t)acc[nt][mt][2]; o[3] = (bf16_t)acc[nt][mt][3];
            *(bf16x4*)(Qd + (i0 + m) * 128 + nb) = o;
        }
    }
}

__global__ __launch_bounds__(256) void k_out(const float* __restrict__ h, const float* __restrict__ W_out,
                                             const float* __restrict__ b_out, float* __restrict__ out) {
    int idx = blockIdx.x * 256 + threadIdx.x;   // < BN*9
    int row = idx / 9, o = idx - row * 9;
    const float* hr = h + (size_t)row * 128;
    float s = b_out[o];
    #pragma unroll 4
    for (int k = 0; k < 128; k++) s += hr[k] * W_out[k * 9 + o];
    out[idx] = s;
}

extern "C" void kernel_launch(void* const* d_in, const int* in_sizes, int n_in,
                              void* d_out, int out_size, void* d_ws, size_t ws_size,
                              hipStream_t stream) {
    const float* x    = (const float*)d_in[0];
    const int*   src  = (const int*)d_in[1];
    const float* W_in = (const float*)d_in[3];
    const float* b_in = (const float*)d_in[4];
    const float* pos  = (const float*)d_in[5];
    const float* mW0  = (const float*)d_in[6];
    const float* mb0  = (const float*)d_in[7];
    const float* mW1  = (const float*)d_in[8];
    const float* mb1  = (const float*)d_in[9];
    const float* mW2  = (const float*)d_in[10];
    const float* mb2  = (const float*)d_in[11];
    const float* mW3  = (const float*)d_in[12];
    const float* mb3  = (const float*)d_in[13];
    const float* nW0  = (const float*)d_in[14];
    const float* nb0  = (const float*)d_in[15];
    const float* nW1  = (const float*)d_in[16];
    const float* nb1  = (const float*)d_in[17];
    const float* nW2  = (const float*)d_in[18];
    const float* nb2  = (const float*)d_in[19];
    const float* nW3  = (const float*)d_in[20];
    const float* nb3  = (const float*)d_in[21];
    const float* ln_g = (const float*)d_in[22];
    const float* ln_b = (const float*)d_in[23];
    const float* W_out= (const float*)d_in[24];
    const float* b_out= (const float*)d_in[25];

    char* ws = (char*)d_ws;
    float*  h   = (float*)ws;                       // 21,233,664 B (also x_embed)
    float*  C2  = (float*)(ws + 21233664);          // 21,233,664 B
    bf16_t* SA  = (bf16_t*)(ws + 42467328);         // 10,616,832 B
    bf16_t* P   = (bf16_t*)(ws + 53084160);         // 10,616,832 B
    bf16_t* Q   = (bf16_t*)(ws + 63700992);         // 10,616,832 B
    bf16_t* Wp  = (bf16_t*)(ws + 74317824);         // 10 * 32,768 B (packed bf16)
    float*  bfix= (float*)(ws + 74645504);          // 512 B

    k_embed<<<20736, 256, 0, stream>>>(x, W_in, b_in, pos, h);

    // packed slots: 0=mW0a 1=mW0b 2=mW1 3=mW2 4=nW0a(h) 5=Ft 6=nW1 7=nW2 8=nW3 9=nW0b(x)
    const float* psrc[9] = {mW0, mW0 + 16384, mW1, mW2, nW0, nW1, nW2, nW3, nW0 + 16384};
    const int    pslot[9] = {0, 1, 2, 3, 4, 6, 7, 8, 9};
    for (int i = 0; i < 9; i++)
        k_pack<<<64, 256, 0, stream>>>(psrc[i], Wp + pslot[i] * 16384);
    k_fuse<<<64, 256, 0, stream>>>(mW3, nW0, Wp + 5 * 16384);
    k_bias<<<1, 128, 0, stream>>>(nb0, mb3, nW0, bfix);

    k_simple_gemm<false><<<324, 256, 0, stream>>>(h, Wp + 9 * 16384, bfix, C2);   // C2
    k_simple_gemm<true ><<<324, 256, 0, stream>>>(h, Wp + 0 * 16384, nullptr, P); // P0
    k_simple_gemm<true ><<<324, 256, 0, stream>>>(h, Wp + 1 * 16384, nullptr, Q); // Q0

    for (int s = 0; s < 16; s++) {
        k_edge<<<dim3(14, 512), 256, 0, stream>>>(P, Q, src, Wp, mb0, mb1, mb2, SA);
        k_node<<<1296, 256, 0, stream>>>(h, SA, C2, Wp, nb1, nb2, nb3, ln_g, ln_b, P, Q);
    }
    k_out<<<1458, 256, 0, stream>>>(h, W_out, b_out, (float*)d_out);
}